// Round 9
// baseline (119.295 us; speedup 1.0000x reference)
//
#include <hip/hip_runtime.h>
#include <hip/hip_bf16.h>
#include <math.h>

// Problem constants
#define Bz    4
#define Cch   192
#define Nn    4096
#define BN    16384      // Bz*Nn
#define Ecnt  262144     // Bz*Nn*16
#define COUT  384
#define CAP   64         // max degree capacity (random 262144->16384 bins: max ~34)

typedef __attribute__((ext_vector_type(8))) short short8;
typedef __attribute__((ext_vector_type(4))) float floatx4;

__device__ __forceinline__ void gload_lds16(const void* g, void* l) {
    __builtin_amdgcn_global_load_lds(
        (const __attribute__((address_space(1))) unsigned int*)g,
        (__attribute__((address_space(3))) unsigned int*)l, 16, 0, 0);
}

__device__ __forceinline__ float b2f(unsigned short u) {
    union { unsigned int i; float f; } z; z.i = ((unsigned int)u) << 16; return z.f;
}
__device__ __forceinline__ unsigned short f2b(float f) {
    __hip_bfloat16 h = __float2bfloat16(f);
    return *(unsigned short*)&h;
}

// ---------------------------------------------------------------------------
// Fused prep (round-4 proven): [0,3072) transpose x->xb bf16; [3072,3360) W
// deinterleave; [3360,3424) zero deg; [3424] int64-vs-int32 detect.
__global__ __launch_bounds__(256) void prep_kernel(
    const float* __restrict__ x, const unsigned int* __restrict__ ew,
    const float* __restrict__ W, __hip_bfloat16* __restrict__ xb,
    __hip_bfloat16* __restrict__ Wx, __hip_bfloat16* __restrict__ Wa,
    int* __restrict__ deg, int* __restrict__ flag) {
    int bid = blockIdx.x;
    if (bid < 3072) {
        __shared__ float tile[32][33];
        int b = bid / 768;
        int r = bid - b * 768;
        int c0 = (r >> 7) * 32;         // 6 c-tiles
        int n0 = (r & 127) * 32;        // 128 n-tiles
        int tx = threadIdx.x & 31, ty = threadIdx.x >> 5;
        for (int i = ty; i < 32; i += 8)
            tile[i][tx] = x[((size_t)(b * Cch + c0 + i)) * Nn + n0 + tx];
        __syncthreads();
        for (int i = ty; i < 32; i += 8)
            xb[((size_t)(b * Nn + n0 + i)) * Cch + c0 + tx] =
                __float2bfloat16(tile[tx][i]);
    } else if (bid < 3360) {
        int i = (bid - 3072) * 256 + threadIdx.x;   // exactly COUT*Cch = 73728
        int o = i / Cch, c = i - o * Cch;
        Wx[i] = __float2bfloat16(W[o * 2 * Cch + 2 * c]);
        Wa[i] = __float2bfloat16(W[o * 2 * Cch + 2 * c + 1]);
    } else if (bid < 3424) {
        deg[(bid - 3360) * 256 + threadIdx.x] = 0;  // exactly BN = 16384
    } else {
        __shared__ int s;
        if (threadIdx.x == 0) s = 1;
        __syncthreads();
        if (ew[2 * threadIdx.x + 1] != 0u) atomicAnd(&s, 0);
        __syncthreads();
        if (threadIdx.x == 0) *flag = s;
    }
}

// ---------------------------------------------------------------------------
// Count degree + place src into fixed-capacity slot table. 2 edges/thread.
__global__ __launch_bounds__(256) void fill_kernel(
    const int* __restrict__ ew, const int* __restrict__ flag,
    int* __restrict__ deg, int* __restrict__ slots) {
    int t = blockIdx.x * 256 + threadIdx.x;   // [0, Ecnt/2)
    int d0, d1, s0, s1;
    if (*flag) {    // int64: dst e -> word 2e; src e -> word 2*Ecnt + 2e
        int4 dv = *(const int4*)&ew[4 * t];
        int4 sv = *(const int4*)&ew[2 * Ecnt + 4 * t];
        d0 = dv.x; d1 = dv.z; s0 = sv.x; s1 = sv.z;
    } else {        // int32
        int2 dv = *(const int2*)&ew[2 * t];
        int2 sv = *(const int2*)&ew[Ecnt + 2 * t];
        d0 = dv.x; d1 = dv.y; s0 = sv.x; s1 = sv.y;
    }
    int p0 = atomicAdd(&deg[d0], 1); if (p0 < CAP) slots[(d0 << 6) + p0] = s0;
    int p1 = atomicAdd(&deg[d1], 1); if (p1 < CAP) slots[(d1 << 6) + p1] = s1;
}

// ---------------------------------------------------------------------------
// aggb[node][c] = (d>0) ? max_{s in N(node)} xb[s][c] - xb[node][c] : 0
// TWO nodes per wave (8/block, grid BN/8): interleaved gather chains give 8
// outstanding loads per group. Clamped-shuffle handles tails/d==0 without
// branches: index min(k+j, d-1) re-loads the last neighbor row (L1-hot,
// max-idempotent); d==0 result discarded by the (d>0) select.
__global__ __launch_bounds__(256) void agg_kernel(
    const int* __restrict__ deg, const int* __restrict__ slots,
    const __hip_bfloat16* __restrict__ xb, __hip_bfloat16* __restrict__ aggb) {
    int lane = threadIdx.x & 63, wave = threadIdx.x >> 6;
    int nA = (blockIdx.x << 3) + (wave << 1);
    int nB = nA + 1;
    int dA = deg[nA]; if (dA > CAP) dA = CAP;
    int dB = deg[nB]; if (dB > CAP) dB = CAP;
    int nbrA = 0, nbrB = 0;
    if (lane < dA) nbrA = slots[(nA << 6) + lane];
    if (lane < dB) nbrB = slots[(nB << 6) + lane];
    const unsigned short* xbu = (const unsigned short*)xb;
    int act = lane < 48;
    int cb = lane * 4;
    int cA = (dA > 0) ? (dA - 1) : 0;
    int cB = (dB > 0) ? (dB - 1) : 0;
    int dmax = (dA > dB) ? dA : dB;
    float a0 = -INFINITY, a1 = -INFINITY, a2 = -INFINITY, a3 = -INFINITY;
    float b0 = -INFINITY, b1 = -INFINITY, b2 = -INFINITY, b3 = -INFINITY;
    for (int k = 0; k < dmax; k += 4) {
        int sA0 = __shfl(nbrA, min(k,     cA));
        int sA1 = __shfl(nbrA, min(k + 1, cA));
        int sA2 = __shfl(nbrA, min(k + 2, cA));
        int sA3 = __shfl(nbrA, min(k + 3, cA));
        int sB0 = __shfl(nbrB, min(k,     cB));
        int sB1 = __shfl(nbrB, min(k + 1, cB));
        int sB2 = __shfl(nbrB, min(k + 2, cB));
        int sB3 = __shfl(nbrB, min(k + 3, cB));
        if (act) {
            ushort4 vA0 = *(const ushort4*)&xbu[sA0 * Cch + cb];
            ushort4 vA1 = *(const ushort4*)&xbu[sA1 * Cch + cb];
            ushort4 vA2 = *(const ushort4*)&xbu[sA2 * Cch + cb];
            ushort4 vA3 = *(const ushort4*)&xbu[sA3 * Cch + cb];
            ushort4 vB0 = *(const ushort4*)&xbu[sB0 * Cch + cb];
            ushort4 vB1 = *(const ushort4*)&xbu[sB1 * Cch + cb];
            ushort4 vB2 = *(const ushort4*)&xbu[sB2 * Cch + cb];
            ushort4 vB3 = *(const ushort4*)&xbu[sB3 * Cch + cb];
            a0 = fmaxf(fmaxf(a0, b2f(vA0.x)), fmaxf(fmaxf(b2f(vA1.x), b2f(vA2.x)), b2f(vA3.x)));
            a1 = fmaxf(fmaxf(a1, b2f(vA0.y)), fmaxf(fmaxf(b2f(vA1.y), b2f(vA2.y)), b2f(vA3.y)));
            a2 = fmaxf(fmaxf(a2, b2f(vA0.z)), fmaxf(fmaxf(b2f(vA1.z), b2f(vA2.z)), b2f(vA3.z)));
            a3 = fmaxf(fmaxf(a3, b2f(vA0.w)), fmaxf(fmaxf(b2f(vA1.w), b2f(vA2.w)), b2f(vA3.w)));
            b0 = fmaxf(fmaxf(b0, b2f(vB0.x)), fmaxf(fmaxf(b2f(vB1.x), b2f(vB2.x)), b2f(vB3.x)));
            b1 = fmaxf(fmaxf(b1, b2f(vB0.y)), fmaxf(fmaxf(b2f(vB1.y), b2f(vB2.y)), b2f(vB3.y)));
            b2 = fmaxf(fmaxf(b2, b2f(vB0.z)), fmaxf(fmaxf(b2f(vB1.z), b2f(vB2.z)), b2f(vB3.z)));
            b3 = fmaxf(fmaxf(b3, b2f(vB0.w)), fmaxf(fmaxf(b2f(vB1.w), b2f(vB2.w)), b2f(vB3.w)));
        }
    }
    if (act) {
        ushort4 xA = *(const ushort4*)&xbu[nA * Cch + cb];
        ushort4 xB = *(const ushort4*)&xbu[nB * Cch + cb];
        ushort4 oA, oB;
        oA.x = (dA > 0) ? f2b(a0 - b2f(xA.x)) : 0;
        oA.y = (dA > 0) ? f2b(a1 - b2f(xA.y)) : 0;
        oA.z = (dA > 0) ? f2b(a2 - b2f(xA.z)) : 0;
        oA.w = (dA > 0) ? f2b(a3 - b2f(xA.w)) : 0;
        oB.x = (dB > 0) ? f2b(b0 - b2f(xB.x)) : 0;
        oB.y = (dB > 0) ? f2b(b1 - b2f(xB.y)) : 0;
        oB.z = (dB > 0) ? f2b(b2 - b2f(xB.z)) : 0;
        oB.w = (dB > 0) ? f2b(b3 - b2f(xB.w)) : 0;
        *(ushort4*)&((unsigned short*)aggb)[nA * Cch + cb] = oA;
        *(ushort4*)&((unsigned short*)aggb)[nB * Cch + cb] = oB;
    }
}

// ---------------------------------------------------------------------------
// out[b][o][n] = relu( Wx[o]·xb[node] + Wa[o]·agg[node] + bias[o] )
// 64(node) x 128(o) tile; grid (256,3); 4 waves (wm=node-half, wn=o-half).
__global__ __launch_bounds__(256) void gemm_kernel(
    const __hip_bfloat16* __restrict__ Xb, const __hip_bfloat16* __restrict__ Ab,
    const __hip_bfloat16* __restrict__ Wx, const __hip_bfloat16* __restrict__ Wa,
    const float* __restrict__ bias, float* __restrict__ out) {
    __shared__ short As[64 * 32];    // 4 KB  [node][k]
    __shared__ short Bs[128 * 32];   // 8 KB  [o][k]
    int t = threadIdx.x;
    int node0 = blockIdx.x * 64;
    int o0    = blockIdx.y * 128;
    int lane = t & 63, wave = t >> 6;
    int quad = lane >> 4, lrow = lane & 15;
    int wm = wave & 1, wn = wave >> 1;

    floatx4 acc[2][4] = {};
    int srow = t >> 2;             // 0..63 (4 threads per row)
    int koff = (t & 3) * 8;        // 0,8,16,24 elements within 32-k tile

    const __hip_bfloat16* Asrc[2] = {Xb, Ab};
    const __hip_bfloat16* Bsrc[2] = {Wx, Wa};

    for (int seg = 0; seg < 2; seg++) {
        const __hip_bfloat16* a_g = Asrc[seg] + (size_t)(node0 + srow) * Cch + koff;
        const __hip_bfloat16* b_g = Bsrc[seg] + (size_t)(o0 + srow) * Cch + koff;
        for (int kt = 0; kt < Cch; kt += 32) {
            __syncthreads();
            gload_lds16(a_g + kt,                    &As[t * 8]);
            gload_lds16(b_g + kt,                    &Bs[t * 8]);
            gload_lds16(b_g + kt + (size_t)64 * Cch, &Bs[2048 + t * 8]);
            __syncthreads();
            short8 af[2], bf[4];
#pragma unroll
            for (int i = 0; i < 2; i++)
                af[i] = *(const short8*)&As[(wm * 32 + i * 16 + lrow) * 32 + quad * 8];
#pragma unroll
            for (int j = 0; j < 4; j++)
                bf[j] = *(const short8*)&Bs[(wn * 64 + j * 16 + lrow) * 32 + quad * 8];
#pragma unroll
            for (int i = 0; i < 2; i++)
#pragma unroll
                for (int j = 0; j < 4; j++)
                    acc[i][j] = __builtin_amdgcn_mfma_f32_16x16x32_bf16(bf[j], af[i], acc[i][j], 0, 0, 0);
        }
    }

    // D layout: col(lane&15)=node, row(quad*4+r)=o
#pragma unroll
    for (int i = 0; i < 2; i++) {
        int node = node0 + wm * 32 + i * 16 + lrow;
        int b = node >> 12, n = node & 4095;
#pragma unroll
        for (int j = 0; j < 4; j++) {
            int ob = o0 + wn * 64 + j * 16 + quad * 4;
#pragma unroll
            for (int r = 0; r < 4; r++) {
                int o = ob + r;
                float v = acc[i][j][r] + bias[o];
                out[((size_t)(b * COUT + o)) * Nn + n] = fmaxf(v, 0.0f);
            }
        }
    }
}

// ---------------------------------------------------------------------------
extern "C" void kernel_launch(void* const* d_in, const int* in_sizes, int n_in,
                              void* d_out, int out_size, void* d_ws, size_t ws_size,
                              hipStream_t stream) {
    const float* x    = (const float*)d_in[0];
    const int*   ew   = (const int*)d_in[1];
    const float* W    = (const float*)d_in[2];
    const float* bias = (const float*)d_in[3];
    float* out        = (float*)d_out;

    char* ws = (char*)d_ws;
    __hip_bfloat16* xb   = (__hip_bfloat16*)ws;                       // 6291456 B
    __hip_bfloat16* aggb = (__hip_bfloat16*)(ws + 6291456);           // 6291456 B
    __hip_bfloat16* Wx   = (__hip_bfloat16*)(ws + 12582912);          // 147456 B
    __hip_bfloat16* Wa   = (__hip_bfloat16*)(ws + 12730368);          // 147456 B
    int* deg   = (int*)(ws + 12877824);                               // 65536 B
    int* slots = (int*)(ws + 12943360);                               // 4194304 B
    int* flag  = (int*)(ws + 17137664);                               // 4 B

    prep_kernel<<<3425, 256, 0, stream>>>(x, (const unsigned int*)ew, W, xb, Wx, Wa, deg, flag);
    fill_kernel<<<Ecnt / 512, 256, 0, stream>>>(ew, flag, deg, slots);
    agg_kernel<<<BN / 8, 256, 0, stream>>>(deg, slots, xb, aggb);
    gemm_kernel<<<dim3(BN / 64, COUT / 128), 256, 0, stream>>>(xb, aggb, Wx, Wa, bias, out);
}

// Round 10
// 115.347 us; speedup vs baseline: 1.0342x; 1.0342x over previous
//
#include <hip/hip_runtime.h>
#include <hip/hip_bf16.h>
#include <math.h>

// Problem constants
#define Bz    4
#define Cch   192
#define Nn    4096
#define BN    16384      // Bz*Nn
#define Ecnt  262144     // Bz*Nn*16
#define COUT  384
#define CAP   64         // max degree capacity (random 262144->16384 bins: max ~34)

typedef __attribute__((ext_vector_type(8))) short short8;
typedef __attribute__((ext_vector_type(4))) float floatx4;

__device__ __forceinline__ void gload_lds16(const void* g, void* l) {
    __builtin_amdgcn_global_load_lds(
        (const __attribute__((address_space(1))) unsigned int*)g,
        (__attribute__((address_space(3))) unsigned int*)l, 16, 0, 0);
}

__device__ __forceinline__ float b2f(unsigned short u) {
    union { unsigned int i; float f; } z; z.i = ((unsigned int)u) << 16; return z.f;
}
__device__ __forceinline__ unsigned short f2b(float f) {
    __hip_bfloat16 h = __float2bfloat16(f);
    return *(unsigned short*)&h;
}

// ---------------------------------------------------------------------------
// Fused prep: [0,3072) transpose x->xb bf16; [3072,3360) W -> Wxa=bf16(Wx-Wa),
// Wa=bf16(Wa); [3360,3424) zero deg; [3424] int64-vs-int32 detect.
// Algebra: out = Wx·x + Wa·(M-x) = (Wx-Wa)·x + Wa·M', M' = (d>0 ? max : x).
__global__ __launch_bounds__(256) void prep_kernel(
    const float* __restrict__ x, const unsigned int* __restrict__ ew,
    const float* __restrict__ W, __hip_bfloat16* __restrict__ xb,
    __hip_bfloat16* __restrict__ Wxa, __hip_bfloat16* __restrict__ Wa,
    int* __restrict__ deg, int* __restrict__ flag) {
    int bid = blockIdx.x;
    if (bid < 3072) {
        __shared__ float tile[32][33];
        int b = bid / 768;
        int r = bid - b * 768;
        int c0 = (r >> 7) * 32;         // 6 c-tiles
        int n0 = (r & 127) * 32;        // 128 n-tiles
        int tx = threadIdx.x & 31, ty = threadIdx.x >> 5;
        for (int i = ty; i < 32; i += 8)
            tile[i][tx] = x[((size_t)(b * Cch + c0 + i)) * Nn + n0 + tx];
        __syncthreads();
        for (int i = ty; i < 32; i += 8)
            xb[((size_t)(b * Nn + n0 + i)) * Cch + c0 + tx] =
                __float2bfloat16(tile[tx][i]);
    } else if (bid < 3360) {
        int i = (bid - 3072) * 256 + threadIdx.x;   // exactly COUT*Cch = 73728
        int o = i / Cch, c = i - o * Cch;
        float wx = W[o * 2 * Cch + 2 * c];
        float wa = W[o * 2 * Cch + 2 * c + 1];
        Wxa[i] = __float2bfloat16(wx - wa);          // fp32 difference, one rounding
        Wa[i]  = __float2bfloat16(wa);
    } else if (bid < 3424) {
        deg[(bid - 3360) * 256 + threadIdx.x] = 0;  // exactly BN = 16384
    } else {
        __shared__ int s;
        if (threadIdx.x == 0) s = 1;
        __syncthreads();
        if (ew[2 * threadIdx.x + 1] != 0u) atomicAnd(&s, 0);
        __syncthreads();
        if (threadIdx.x == 0) *flag = s;
    }
}

// ---------------------------------------------------------------------------
// Count degree + place src into fixed-capacity slot table. 2 edges/thread.
__global__ __launch_bounds__(256) void fill_kernel(
    const int* __restrict__ ew, const int* __restrict__ flag,
    int* __restrict__ deg, int* __restrict__ slots) {
    int t = blockIdx.x * 256 + threadIdx.x;   // [0, Ecnt/2)
    int d0, d1, s0, s1;
    if (*flag) {    // int64: dst e -> word 2e; src e -> word 2*Ecnt + 2e
        int4 dv = *(const int4*)&ew[4 * t];
        int4 sv = *(const int4*)&ew[2 * Ecnt + 4 * t];
        d0 = dv.x; d1 = dv.z; s0 = sv.x; s1 = sv.z;
    } else {        // int32
        int2 dv = *(const int2*)&ew[2 * t];
        int2 sv = *(const int2*)&ew[Ecnt + 2 * t];
        d0 = dv.x; d1 = dv.y; s0 = sv.x; s1 = sv.y;
    }
    int p0 = atomicAdd(&deg[d0], 1); if (p0 < CAP) slots[(d0 << 6) + p0] = s0;
    int p1 = atomicAdd(&deg[d1], 1); if (p1 < CAP) slots[(d1 << 6) + p1] = s1;
}

// ---------------------------------------------------------------------------
// Mb[node][c] = (d>0) ? max_{s in N(node)} xb[s][c] : xb[node][c]
// (R8-proven 1 node/wave; subtraction folded into the GEMM via Wxa.)
__global__ __launch_bounds__(256) void agg_kernel(
    const int* __restrict__ deg, const int* __restrict__ slots,
    const __hip_bfloat16* __restrict__ xb, __hip_bfloat16* __restrict__ Mb) {
    int lane = threadIdx.x & 63, wave = threadIdx.x >> 6;
    int node = (blockIdx.x << 2) + wave;
    int d = deg[node]; if (d > CAP) d = CAP;
    int nbrval = 0;
    if (lane < d) nbrval = slots[(node << 6) + lane];
    const unsigned short* xbu = (const unsigned short*)xb;
    int act = lane < 48;
    int cb = lane * 4;
    float m0 = -INFINITY, m1 = -INFINITY, m2 = -INFINITY, m3 = -INFINITY;
    int k = 0;
    for (; k + 4 <= d; k += 4) {
        int s0 = __shfl(nbrval, k);
        int s1 = __shfl(nbrval, k + 1);
        int s2 = __shfl(nbrval, k + 2);
        int s3 = __shfl(nbrval, k + 3);
        if (act) {
            ushort4 v0 = *(const ushort4*)&xbu[s0 * Cch + cb];
            ushort4 v1 = *(const ushort4*)&xbu[s1 * Cch + cb];
            ushort4 v2 = *(const ushort4*)&xbu[s2 * Cch + cb];
            ushort4 v3 = *(const ushort4*)&xbu[s3 * Cch + cb];
            m0 = fmaxf(fmaxf(m0, b2f(v0.x)), fmaxf(fmaxf(b2f(v1.x), b2f(v2.x)), b2f(v3.x)));
            m1 = fmaxf(fmaxf(m1, b2f(v0.y)), fmaxf(fmaxf(b2f(v1.y), b2f(v2.y)), b2f(v3.y)));
            m2 = fmaxf(fmaxf(m2, b2f(v0.z)), fmaxf(fmaxf(b2f(v1.z), b2f(v2.z)), b2f(v3.z)));
            m3 = fmaxf(fmaxf(m3, b2f(v0.w)), fmaxf(fmaxf(b2f(v1.w), b2f(v2.w)), b2f(v3.w)));
        }
    }
    for (; k < d; k++) {
        int s = __shfl(nbrval, k);
        if (act) {
            ushort4 v = *(const ushort4*)&xbu[s * Cch + cb];
            m0 = fmaxf(m0, b2f(v.x)); m1 = fmaxf(m1, b2f(v.y));
            m2 = fmaxf(m2, b2f(v.z)); m3 = fmaxf(m3, b2f(v.w));
        }
    }
    if (act) {
        ushort4 o4;
        if (d > 0) {                         // wave-uniform branch
            o4.x = f2b(m0); o4.y = f2b(m1); o4.z = f2b(m2); o4.w = f2b(m3);
        } else {                             // empty segment: M' = x (cancels in GEMM)
            o4 = *(const ushort4*)&xbu[node * Cch + cb];
        }
        *(ushort4*)&((unsigned short*)Mb)[node * Cch + cb] = o4;
    }
}

// ---------------------------------------------------------------------------
// out[b][o][n] = relu( Wxa[o]·xb[node] + Wa[o]·Mb[node] + bias[o] )
// 64(node) x 128(o) tile; grid (256,3); 4 waves (wm=node-half, wn=o-half).
__global__ __launch_bounds__(256) void gemm_kernel(
    const __hip_bfloat16* __restrict__ Xb, const __hip_bfloat16* __restrict__ Ab,
    const __hip_bfloat16* __restrict__ Wxa, const __hip_bfloat16* __restrict__ Wa,
    const float* __restrict__ bias, float* __restrict__ out) {
    __shared__ short As[64 * 32];    // 4 KB  [node][k]
    __shared__ short Bs[128 * 32];   // 8 KB  [o][k]
    int t = threadIdx.x;
    int node0 = blockIdx.x * 64;
    int o0    = blockIdx.y * 128;
    int lane = t & 63, wave = t >> 6;
    int quad = lane >> 4, lrow = lane & 15;
    int wm = wave & 1, wn = wave >> 1;

    floatx4 acc[2][4] = {};
    int srow = t >> 2;             // 0..63 (4 threads per row)
    int koff = (t & 3) * 8;        // 0,8,16,24 elements within 32-k tile

    const __hip_bfloat16* Asrc[2] = {Xb, Ab};
    const __hip_bfloat16* Bsrc[2] = {Wxa, Wa};

    for (int seg = 0; seg < 2; seg++) {
        const __hip_bfloat16* a_g = Asrc[seg] + (size_t)(node0 + srow) * Cch + koff;
        const __hip_bfloat16* b_g = Bsrc[seg] + (size_t)(o0 + srow) * Cch + koff;
        for (int kt = 0; kt < Cch; kt += 32) {
            __syncthreads();
            gload_lds16(a_g + kt,                    &As[t * 8]);
            gload_lds16(b_g + kt,                    &Bs[t * 8]);
            gload_lds16(b_g + kt + (size_t)64 * Cch, &Bs[2048 + t * 8]);
            __syncthreads();
            short8 af[2], bf[4];
#pragma unroll
            for (int i = 0; i < 2; i++)
                af[i] = *(const short8*)&As[(wm * 32 + i * 16 + lrow) * 32 + quad * 8];
#pragma unroll
            for (int j = 0; j < 4; j++)
                bf[j] = *(const short8*)&Bs[(wn * 64 + j * 16 + lrow) * 32 + quad * 8];
#pragma unroll
            for (int i = 0; i < 2; i++)
#pragma unroll
                for (int j = 0; j < 4; j++)
                    acc[i][j] = __builtin_amdgcn_mfma_f32_16x16x32_bf16(bf[j], af[i], acc[i][j], 0, 0, 0);
        }
    }

    // D layout: col(lane&15)=node, row(quad*4+r)=o
#pragma unroll
    for (int i = 0; i < 2; i++) {
        int node = node0 + wm * 32 + i * 16 + lrow;
        int b = node >> 12, n = node & 4095;
#pragma unroll
        for (int j = 0; j < 4; j++) {
            int ob = o0 + wn * 64 + j * 16 + quad * 4;
#pragma unroll
            for (int r = 0; r < 4; r++) {
                int o = ob + r;
                float v = acc[i][j][r] + bias[o];
                out[((size_t)(b * COUT + o)) * Nn + n] = fmaxf(v, 0.0f);
            }
        }
    }
}

// ---------------------------------------------------------------------------
extern "C" void kernel_launch(void* const* d_in, const int* in_sizes, int n_in,
                              void* d_out, int out_size, void* d_ws, size_t ws_size,
                              hipStream_t stream) {
    const float* x    = (const float*)d_in[0];
    const int*   ew   = (const int*)d_in[1];
    const float* W    = (const float*)d_in[2];
    const float* bias = (const float*)d_in[3];
    float* out        = (float*)d_out;

    char* ws = (char*)d_ws;
    __hip_bfloat16* xb   = (__hip_bfloat16*)ws;                       // 6291456 B
    __hip_bfloat16* Mb   = (__hip_bfloat16*)(ws + 6291456);           // 6291456 B
    __hip_bfloat16* Wxa  = (__hip_bfloat16*)(ws + 12582912);          // 147456 B
    __hip_bfloat16* Wa   = (__hip_bfloat16*)(ws + 12730368);          // 147456 B
    int* deg   = (int*)(ws + 12877824);                               // 65536 B
    int* slots = (int*)(ws + 12943360);                               // 4194304 B
    int* flag  = (int*)(ws + 17137664);                               // 4 B

    prep_kernel<<<3425, 256, 0, stream>>>(x, (const unsigned int*)ew, W, xb, Wxa, Wa, deg, flag);
    fill_kernel<<<Ecnt / 512, 256, 0, stream>>>(ew, flag, deg, slots);
    agg_kernel<<<BN / 4, 256, 0, stream>>>(deg, slots, xb, Mb);
    gemm_kernel<<<dim3(BN / 64, COUT / 128), 256, 0, stream>>>(xb, Mb, Wxa, Wa, bias, out);
}